// Round 1
// baseline (342.645 us; speedup 1.0000x reference)
//
#include <hip/hip_runtime.h>

#define B 2
#define N 768
#define DIM 512
#define DE 64
#define LN_EPS 1e-5f

// Workspace layout (floats):
//   Rc  : [B*N*DE]      centered R = (x W_r^T) W_e^T - mean
//   Cc  : [B*N*DE]      centered C
//   ssqR: [B*N]         sum(Rc^2) per token
//   ssqC: [B*N]
#define OFF_RC   0
#define OFF_CC   (B*N*DE)
#define OFF_SSR  (2*B*N*DE)
#define OFF_SSC  (2*B*N*DE + B*N)

// Kernel 1: per token, compute rows/cols (64-dim each), then R/C via W_edges,
// then center + sum-of-squares. One block (256 thr) per token.
__global__ __launch_bounds__(256) void ee_precompute(
    const float* __restrict__ x, const float* __restrict__ Wr,
    const float* __restrict__ Wc, const float* __restrict__ We,
    float* __restrict__ Rc, float* __restrict__ Cc,
    float* __restrict__ ssqR, float* __restrict__ ssqC)
{
    __shared__ float xs[DIM];
    __shared__ float rc[2 * DE];   // rows[0..63], cols[64..127]

    const int tok = blockIdx.x;              // b*N + t
    const int tid = threadIdx.x;
    const int lane = tid & 63;
    const int wave = tid >> 6;

    const float* xp = x + (size_t)tok * DIM;
    xs[tid]       = xp[tid];
    xs[tid + 256] = xp[tid + 256];
    __syncthreads();

    // Phase B: 128 dot products of length 512. Wave w handles outputs
    // o = w*32 .. w*32+31. Lane covers 8 contiguous elements (2x float4).
    const float4 b0 = *(const float4*)(xs + lane * 8);
    const float4 b1 = *(const float4*)(xs + lane * 8 + 4);
    for (int m = 0; m < 32; ++m) {
        const int o = wave * 32 + m;
        const float* W = (o < DE) ? (Wr + (size_t)o * DIM)
                                  : (Wc + (size_t)(o - DE) * DIM);
        const float4 a0 = *(const float4*)(W + lane * 8);
        const float4 a1 = *(const float4*)(W + lane * 8 + 4);
        float p = a0.x*b0.x + a0.y*b0.y + a0.z*b0.z + a0.w*b0.w
                + a1.x*b1.x + a1.y*b1.y + a1.z*b1.z + a1.w*b1.w;
        #pragma unroll
        for (int s = 1; s < 64; s <<= 1) p += __shfl_xor(p, s);
        if (lane == 0) rc[o] = p;
    }
    __syncthreads();

    // Phase C+D: waves 0/1 compute R[f]/C[f] then center + ssq.
    if (tid < 128) {
        const int f = lane;
        const float* W = We + (size_t)f * DE;       // We[f, e]
        const float* rcp = (wave == 0) ? rc : (rc + DE);
        float acc = 0.f;
        #pragma unroll
        for (int e4 = 0; e4 < DE / 4; ++e4) {
            const float4 w4 = *(const float4*)(W + e4 * 4);
            const float4 r4 = *(const float4*)(rcp + e4 * 4);
            acc += w4.x*r4.x + w4.y*r4.y + w4.z*r4.z + w4.w*r4.w;
        }
        float mu = acc;
        #pragma unroll
        for (int s = 1; s < 64; s <<= 1) mu += __shfl_xor(mu, s);
        mu *= (1.f / DE);
        const float c = acc - mu;
        float sq = c * c;
        #pragma unroll
        for (int s = 1; s < 64; s <<= 1) sq += __shfl_xor(sq, s);
        float* dst = ((wave == 0) ? Rc : Cc) + (size_t)tok * DE;
        dst[f] = c;
        if (lane == 0) ((wave == 0) ? ssqR : ssqC)[tok] = sq;
    }
}

// Kernel 2: one block per (b,i) row; each wave handles 4 j's per iteration.
// Lane l: j_sub = l>>4, f-quad = (l&15)*4. 16-lane shfl reduce for the dot.
__global__ __launch_bounds__(256) void ee_outer_ln(
    const float* __restrict__ Rc, const float* __restrict__ Cc,
    const float* __restrict__ ssqRp, const float* __restrict__ ssqCp,
    const float* __restrict__ gamma, const float* __restrict__ beta,
    float* __restrict__ out)
{
    const int bi = blockIdx.x;               // b*N + i
    const int tid = threadIdx.x;
    const int lane = tid & 63;
    const int wave = tid >> 6;
    const int jsub = lane >> 4;
    const int fb = (lane & 15) * 4;

    const int b = bi / N;
    const float* Ccb   = Cc + (size_t)b * N * DE;
    const float* ssqCb = ssqCp + (size_t)b * N;
    float* outb = out + (size_t)bi * N * DE;

    const float ssqR = ssqRp[bi];
    const float4 r  = *(const float4*)(Rc + (size_t)bi * DE + fb);
    const float4 g  = *(const float4*)(gamma + fb);
    const float4 be = *(const float4*)(beta + fb);

    for (int t = 0; t < N / 16; ++t) {
        const int j = t * 16 + wave * 4 + jsub;
        const float4 c = *(const float4*)(Ccb + (size_t)j * DE + fb);
        const float ssqC = ssqCb[j];

        float p = r.x*c.x + r.y*c.y + r.z*c.z + r.w*c.w;
        p += __shfl_xor(p, 1);
        p += __shfl_xor(p, 2);
        p += __shfl_xor(p, 4);
        p += __shfl_xor(p, 8);   // full dot(Rc_i, Cc_j) in all 16 lanes

        const float var = (ssqR + ssqC + 2.f * p) * (1.f / DE);
        const float s = rsqrtf(var + LN_EPS);

        float4 o;
        o.x = (r.x + c.x) * (s * g.x) + be.x;
        o.y = (r.y + c.y) * (s * g.y) + be.y;
        o.z = (r.z + c.z) * (s * g.z) + be.z;
        o.w = (r.w + c.w) * (s * g.w) + be.w;
        *(float4*)(outb + (size_t)j * DE + fb) = o;
    }
}

extern "C" void kernel_launch(void* const* d_in, const int* in_sizes, int n_in,
                              void* d_out, int out_size, void* d_ws, size_t ws_size,
                              hipStream_t stream) {
    const float* x     = (const float*)d_in[0];
    const float* Wr    = (const float*)d_in[1];
    const float* Wc    = (const float*)d_in[2];
    const float* We    = (const float*)d_in[3];
    const float* gamma = (const float*)d_in[4];
    const float* beta  = (const float*)d_in[5];
    float* out = (float*)d_out;
    float* ws  = (float*)d_ws;

    float* Rc   = ws + OFF_RC;
    float* Cc   = ws + OFF_CC;
    float* ssqR = ws + OFF_SSR;
    float* ssqC = ws + OFF_SSC;

    ee_precompute<<<B * N, 256, 0, stream>>>(x, Wr, Wc, We, Rc, Cc, ssqR, ssqC);
    ee_outer_ln<<<B * N, 256, 0, stream>>>(Rc, Cc, ssqR, ssqC, gamma, beta, out);
}